// Round 2
// baseline (636.337 us; speedup 1.0000x reference)
//
#include <hip/hip_runtime.h>

#define BATCH 16
#define CIN 512
#define COUT 512
#define RES 64

typedef __attribute__((ext_vector_type(8))) short bf16x8;
typedef __attribute__((ext_vector_type(4))) float f32x4;

// zero-initialized device global: boundary-tap source for global_load_lds.
// Never written; module load zero-inits; harness never poisons device globals.
__device__ __align__(16) unsigned short g_zero[64];

static __device__ __forceinline__ unsigned short f2bf(float f) {
    unsigned int u = __float_as_uint(f);
    u += 0x7fffu + ((u >> 16) & 1u);   // round-to-nearest-even
    return (unsigned short)(u >> 16);
}

static __device__ __forceinline__ void gload16(const void* g, void* l) {
    __builtin_amdgcn_global_load_lds(
        (const __attribute__((address_space(1))) void*)g,
        (__attribute__((address_space(3))) void*)l, 16, 0, 0);
}

// ---------------- styles[b][i] = sum_k w[b,k]*aw[i,k]*wg + ab[i] ----------------
__global__ void k_styles(const float* __restrict__ w, const float* __restrict__ aw,
                         const float* __restrict__ ab, float* __restrict__ styles) {
    int wid  = (blockIdx.x * blockDim.x + threadIdx.x) >> 6;
    int lane = threadIdx.x & 63;
    int b = wid >> 9, i = wid & 511;
    const float* wrow = w + b * 512;
    const float* arow = aw + (size_t)i * 512;
    float acc = 0.f;
    for (int k = lane; k < 512; k += 64) acc += wrow[k] * arow[k];
    for (int off = 32; off; off >>= 1) acc += __shfl_down(acc, off, 64);
    if (lane == 0) styles[wid] = acc * 0.04419417382415922f + ab[i];
}

// ------- dcoefs[b][o] = rsqrt(sum_i styles[b,i]^2 * sum_k weight[o,i,k]^2 + 1e-8) ----
__global__ void k_dcoefs(const float* __restrict__ weight, const float* __restrict__ styles,
                         float* __restrict__ dcoefs) {
    int wid  = (blockIdx.x * blockDim.x + threadIdx.x) >> 6;
    int lane = threadIdx.x & 63;
    int b = wid >> 9, o = wid & 511;
    const float* wrow = weight + (size_t)o * 4608;
    const float* srow = styles + b * 512;
    float acc = 0.f;
    for (int i = lane; i < 512; i += 64) {
        float s = srow[i];
        float ss = 0.f;
#pragma unroll
        for (int k = 0; k < 9; ++k) { float v = wrow[i * 9 + k]; ss += v * v; }
        acc += s * s * ss;
    }
    for (int off = 32; off; off >>= 1) acc += __shfl_down(acc, off, 64);
    if (lane == 0) dcoefs[wid] = rsqrtf(acc + 1e-8f);
}

// ---------------- wA[t][o][i] = bf16(weight[o][i][t])  (batch-independent!) ----
__global__ void k_wA(const float* __restrict__ weight, unsigned short* __restrict__ wA) {
    int o = blockIdx.x;
    __shared__ float lw[4608];
    for (int idx = threadIdx.x; idx < 4608; idx += 256)
        lw[idx] = weight[(size_t)o * 4608 + idx];
    __syncthreads();
    int i = threadIdx.x * 2;
#pragma unroll
    for (int t = 0; t < 9; ++t) {
        unsigned* dst = (unsigned*)(wA + (((size_t)t * COUT + o) << 9));
        dst[threadIdx.x] = (unsigned)f2bf(lw[i * 9 + t]) |
                           ((unsigned)f2bf(lw[(i + 1) * 9 + t]) << 16);
    }
}

// ---- xt[b][h][w][i] = bf16(x[b][i][h][w] * styles[b][i])  (CHW->HWC + style fold) ----
__global__ void k_xpose(const float* __restrict__ x, const float* __restrict__ styles,
                        unsigned short* __restrict__ xt) {
    int bh = blockIdx.x;          // b*64 + h
    int ic = blockIdx.y;          // channel chunk of 32
    int b = bh >> 6, h = bh & 63;
    __shared__ float tile[32][65];
    __shared__ float st[32];
    const float* src = x + ((size_t)b * 512 + ic * 32) * 4096 + h * 64;
    if (threadIdx.x < 32) st[threadIdx.x] = styles[b * 512 + ic * 32 + threadIdx.x];
    for (int idx = threadIdx.x; idx < 2048; idx += 256) {
        int c = idx >> 6, w = idx & 63;
        tile[c][w] = src[(size_t)c * 4096 + w];
    }
    __syncthreads();
    int w = threadIdx.x >> 2, cg = (threadIdx.x & 3) * 8;
    bf16x8 v;
#pragma unroll
    for (int j = 0; j < 8; ++j) v[j] = (short)f2bf(tile[cg + j][w] * st[cg + j]);
    *(bf16x8*)(xt + (((size_t)bh * 64 + w) << 9) + ic * 32 + cg) = v;
}

// ---------------- main conv: implicit GEMM, 128x128 tile, mfma 16x16x32 bf16 ----
__global__ __launch_bounds__(256, 2)
void k_conv(const unsigned short* __restrict__ wA, const unsigned short* __restrict__ xt,
            const float* __restrict__ dcoefs,
            const float* __restrict__ noise, const float* __restrict__ nstr,
            const float* __restrict__ bias, float* __restrict__ out) {
    __shared__ __align__(16) unsigned short lA[128 * 32];
    __shared__ __align__(16) unsigned short lB[128 * 32];
    const int tid = threadIdx.x;
    const int lane = tid & 63;
    const int wave = tid >> 6;
    const int b  = blockIdx.z;
    const int o0 = blockIdx.x * 128;
    const int p0 = blockIdx.y * 128;
    const int h0 = p0 >> 6;

    // A staging: wave covers o-rows [o0+wave*32, +32), 32 K-channels (64B) per row
    const unsigned short* gA0 = wA + ((size_t)(o0 + wave * 32 + (lane >> 2))) * 512
                                   + (lane & 3) * 8;
    const unsigned short* gA1 = gA0 + 16 * 512;
    void* ldsA0 = (void*)(lA + wave * 1024);
    void* ldsA1 = (void*)(lA + wave * 1024 + 512);
    void* ldsB0 = (void*)(lB + wave * 1024);
    void* ldsB1 = (void*)(lB + wave * 1024 + 512);

    const int fm_row = (wave >> 1) * 64 + (lane & 15);
    const int fn_row = (wave & 1) * 64 + (lane & 15);
    const int kof = (lane >> 4) * 8;

    f32x4 acc[4][4];
#pragma unroll
    for (int i = 0; i < 4; ++i)
#pragma unroll
        for (int j = 0; j < 4; ++j) acc[i][j] = (f32x4){0.f, 0.f, 0.f, 0.f};

    for (int t = 0; t < 9; ++t) {
        const int dy = t / 3 - 1, dx = t % 3 - 1;
        const unsigned short* gB[2];
        int adv[2];
#pragma unroll
        for (int s = 0; s < 2; ++s) {
            int pp = wave * 32 + s * 16 + (lane >> 2);   // pixel row in tile [0,127]
            int r = pp >> 6, w = pp & 63;
            int h = h0 + r + dy, ww = w + dx;
            bool valid = ((unsigned)h < 64u) && ((unsigned)ww < 64u);
            gB[s] = valid ? xt + (((size_t)b * 64 + h) * 64 + ww) * 512 + (lane & 3) * 8
                          : g_zero + (lane & 3) * 8;
            adv[s] = valid ? 32 : 0;
        }
        for (int i0 = 0; i0 < 16; ++i0) {
            __syncthreads();
            gload16(gA0, ldsA0);
            gload16(gA1, ldsA1);
            gload16(gB[0], ldsB0);
            gload16(gB[1], ldsB1);
            gA0 += 32; gA1 += 32; gB[0] += adv[0]; gB[1] += adv[1];
            asm volatile("s_waitcnt vmcnt(0)" ::: "memory");
            __syncthreads();

            bf16x8 af[4], bfr[4];
#pragma unroll
            for (int f = 0; f < 4; ++f)
                af[f] = *(const bf16x8*)&lA[(fm_row + f * 16) * 32 + kof];
#pragma unroll
            for (int f = 0; f < 4; ++f)
                bfr[f] = *(const bf16x8*)&lB[(fn_row + f * 16) * 32 + kof];
#pragma unroll
            for (int fm = 0; fm < 4; ++fm)
#pragma unroll
                for (int fn = 0; fn < 4; ++fn)
                    acc[fm][fn] = __builtin_amdgcn_mfma_f32_16x16x32_bf16(
                        af[fm], bfr[fn], acc[fm][fn], 0, 0, 0);
        }
        gA0 += 261632; gA1 += 261632;   // next tap (stride COUT*512), minus the 512 advanced
    }

    const float ns = nstr[0];
    const float* dcb = dcoefs + b * 512;
#pragma unroll
    for (int fm = 0; fm < 4; ++fm) {
        int ob = o0 + (wave >> 1) * 64 + fm * 16 + (lane >> 4) * 4;
#pragma unroll
        for (int fn = 0; fn < 4; ++fn) {
            int p = p0 + (wave & 1) * 64 + fn * 16 + (lane & 15);
            float nval = noise[p] * ns;
#pragma unroll
            for (int rg = 0; rg < 4; ++rg) {
                int o = ob + rg;
                float v = acc[fm][fn][rg] * dcb[o] + nval + bias[o];
                v = (v > 0.f ? v : 0.2f * v) * 1.41421356f;
                out[((size_t)(b * COUT + o) << 12) + p] = v;
            }
        }
    }
}

// -------- fallback: fully self-contained fp32 conv (touches NO workspace) --------
__global__ void k_conv_naive(const float* __restrict__ x, const float* __restrict__ w,
                             const float* __restrict__ weight,
                             const float* __restrict__ aw, const float* __restrict__ ab,
                             const float* __restrict__ noise, const float* __restrict__ nstr,
                             const float* __restrict__ bias, float* __restrict__ out) {
    const int o = blockIdx.x, b = blockIdx.y;
    __shared__ float ss[512];
    __shared__ float red[256];
    const float* wv = w + b * 512;
    // styles: 2 rows per thread
    for (int i = threadIdx.x; i < 512; i += 256) {
        const float* arow = aw + (size_t)i * 512;
        float acc = 0.f;
        for (int k = 0; k < 512; ++k) acc += wv[k] * arow[k];
        ss[i] = acc * 0.04419417382415922f + ab[i];
    }
    __syncthreads();
    // dcoef for this (b,o)
    float part = 0.f;
    for (int i = threadIdx.x; i < 512; i += 256) {
        float s = ss[i], sq = 0.f;
#pragma unroll
        for (int k = 0; k < 9; ++k) { float v = weight[((size_t)o * 512 + i) * 9 + k]; sq += v * v; }
        part += s * s * sq;
    }
    red[threadIdx.x] = part;
    __syncthreads();
    for (int st = 128; st; st >>= 1) {
        if (threadIdx.x < st) red[threadIdx.x] += red[threadIdx.x + st];
        __syncthreads();
    }
    const float dcoef = rsqrtf(red[0] + 1e-8f);

    float acc[16];
#pragma unroll
    for (int j = 0; j < 16; ++j) acc[j] = 0.f;
    for (int i = 0; i < 512; ++i) {
        const float s = ss[i];
        float wk[9];
#pragma unroll
        for (int k = 0; k < 9; ++k) wk[k] = weight[((size_t)o * 512 + i) * 9 + k] * s;
        const float* xp = x + ((size_t)b * 512 + i) * 4096;
#pragma unroll
        for (int j = 0; j < 16; ++j) {
            const int p = (j << 8) + threadIdx.x;
            const int h = p >> 6, ww = p & 63;
            float a = acc[j];
#pragma unroll
            for (int ky = 0; ky < 3; ++ky) {
                int hh = h + ky - 1;
                if ((unsigned)hh < 64u) {
#pragma unroll
                    for (int kx = 0; kx < 3; ++kx) {
                        int wv2 = ww + kx - 1;
                        if ((unsigned)wv2 < 64u) a += wk[ky * 3 + kx] * xp[hh * 64 + wv2];
                    }
                }
            }
            acc[j] = a;
        }
    }
    const float ns = nstr[0], bs = bias[o];
#pragma unroll
    for (int j = 0; j < 16; ++j) {
        int p = (j << 8) + threadIdx.x;
        float v = acc[j] * dcoef + noise[p] * ns + bs;
        v = (v > 0.f ? v : 0.2f * v) * 1.41421356f;
        out[((size_t)(b * COUT + o) << 12) + p] = v;
    }
}

extern "C" void kernel_launch(void* const* d_in, const int* in_sizes, int n_in,
                              void* d_out, int out_size, void* d_ws, size_t ws_size,
                              hipStream_t stream) {
    const float* x   = (const float*)d_in[0];
    const float* w   = (const float*)d_in[1];
    const float* wt  = (const float*)d_in[2];
    const float* aw  = (const float*)d_in[3];
    const float* ab  = (const float*)d_in[4];
    const float* bs  = (const float*)d_in[5];
    const float* nc  = (const float*)d_in[6];
    const float* nst = (const float*)d_in[7];
    float* out = (float*)d_out;

    char* ws = (char*)d_ws;
    float* styles = (float*)ws;                                  // 32 KB
    float* dcoefs = (float*)(ws + 32 * 1024);                    // 32 KB
    unsigned short* wA = (unsigned short*)(ws + (1 << 20));      // 4.7 MB
    unsigned short* xt = (unsigned short*)(ws + (1 << 20) + 4718592ull); // 67.1 MB
    const size_t need = (size_t)(1 << 20) + 4718592ull + 67108864ull;    // ~69.5 MB

    if (d_ws != nullptr && ws_size >= need) {
        k_styles<<<2048, 256, 0, stream>>>(w, aw, ab, styles);
        k_dcoefs<<<2048, 256, 0, stream>>>(wt, styles, dcoefs);
        k_wA<<<512, 256, 0, stream>>>(wt, wA);
        k_xpose<<<dim3(1024, 16), 256, 0, stream>>>(x, styles, xt);
        k_conv<<<dim3(4, 32, 16), 256, 0, stream>>>(wA, xt, dcoefs, nc, nst, bs, out);
    } else {
        k_conv_naive<<<dim3(512, 16), 256, 0, stream>>>(x, w, wt, aw, ab, nc, nst, bs, out);
    }
}

// Round 3
// 600.554 us; speedup vs baseline: 1.0596x; 1.0596x over previous
//
#include <hip/hip_runtime.h>

#define BATCH 16
#define CIN 512
#define COUT 512
#define RES 64

typedef __attribute__((ext_vector_type(8))) short bf16x8;
typedef __attribute__((ext_vector_type(4))) float f32x4;

// zero-initialized device global: boundary-tap source for global_load_lds.
__device__ __align__(16) unsigned short g_zero[64];

static __device__ __forceinline__ unsigned short f2bf(float f) {
    unsigned int u = __float_as_uint(f);
    u += 0x7fffu + ((u >> 16) & 1u);   // round-to-nearest-even
    return (unsigned short)(u >> 16);
}

static __device__ __forceinline__ void gload16(const void* g, void* l) {
    __builtin_amdgcn_global_load_lds(
        (const __attribute__((address_space(1))) void*)g,
        (__attribute__((address_space(3))) void*)l, 16, 0, 0);
}

// ---- fused prep1: blocks [0,2048): styles[b][i] ; blocks [2048,2560): wA + wsq ----
__global__ void k_prep1(const float* __restrict__ w, const float* __restrict__ aw,
                        const float* __restrict__ ab, const float* __restrict__ weight,
                        float* __restrict__ styles, unsigned short* __restrict__ wA,
                        float* __restrict__ wsq) {
    if (blockIdx.x < 2048) {
        int wid  = (blockIdx.x * blockDim.x + threadIdx.x) >> 6;
        int lane = threadIdx.x & 63;
        int b = wid >> 9, i = wid & 511;
        const float* wrow = w + b * 512;
        const float* arow = aw + (size_t)i * 512;
        float acc = 0.f;
        for (int k = lane; k < 512; k += 64) acc += wrow[k] * arow[k];
        for (int off = 32; off; off >>= 1) acc += __shfl_down(acc, off, 64);
        if (lane == 0) styles[wid] = acc * 0.04419417382415922f + ab[i];
    } else {
        int o = blockIdx.x - 2048;
        __shared__ float lw[4608];
        for (int idx = threadIdx.x; idx < 4608; idx += 256)
            lw[idx] = weight[(size_t)o * 4608 + idx];
        __syncthreads();
        int i = threadIdx.x * 2;
        float sq0 = 0.f, sq1 = 0.f;
#pragma unroll
        for (int t = 0; t < 9; ++t) {
            float v0 = lw[i * 9 + t], v1 = lw[(i + 1) * 9 + t];
            sq0 += v0 * v0; sq1 += v1 * v1;
            unsigned* dst = (unsigned*)(wA + (((size_t)t * COUT + o) << 9));
            dst[threadIdx.x] = (unsigned)f2bf(v0) | ((unsigned)f2bf(v1) << 16);
        }
        *(float2*)(wsq + ((size_t)o << 9) + i) = make_float2(sq0, sq1);
    }
}

// ---- dcoefs[b][o] = rsqrt(sum_i styles^2 * wsq[o,i] + 1e-8) ----
__global__ void k_dcoefs(const float* __restrict__ wsq, const float* __restrict__ styles,
                         float* __restrict__ dcoefs) {
    int wid  = (blockIdx.x * blockDim.x + threadIdx.x) >> 6;
    int lane = threadIdx.x & 63;
    int b = wid >> 9, o = wid & 511;
    const float* srow = styles + b * 512;
    const float* qrow = wsq + ((size_t)o << 9);
    float acc = 0.f;
    for (int i = lane; i < 512; i += 64) {
        float s = srow[i];
        acc += s * s * qrow[i];
    }
    for (int off = 32; off; off >>= 1) acc += __shfl_down(acc, off, 64);
    if (lane == 0) dcoefs[wid] = rsqrtf(acc + 1e-8f);
}

// ---- xt[b][h][w][i] = bf16(x[b][i][h][w] * styles[b][i])  (CHW->HWC + style fold) ----
__global__ void k_xpose(const float* __restrict__ x, const float* __restrict__ styles,
                        unsigned short* __restrict__ xt) {
    int bh = blockIdx.x;          // b*64 + h
    int ic = blockIdx.y;          // channel chunk of 32
    int b = bh >> 6, h = bh & 63;
    __shared__ float tile[32][65];
    __shared__ float st[32];
    const float* src = x + ((size_t)b * 512 + ic * 32) * 4096 + h * 64;
    if (threadIdx.x < 32) st[threadIdx.x] = styles[b * 512 + ic * 32 + threadIdx.x];
    for (int idx = threadIdx.x; idx < 512; idx += 256) {
        int c = idx >> 4, w4 = (idx & 15) * 4;
        float4 v = *(const float4*)(src + (size_t)c * 4096 + w4);
        tile[c][w4] = v.x; tile[c][w4 + 1] = v.y; tile[c][w4 + 2] = v.z; tile[c][w4 + 3] = v.w;
    }
    __syncthreads();
    int w = threadIdx.x >> 2, cg = (threadIdx.x & 3) * 8;
    bf16x8 v;
#pragma unroll
    for (int j = 0; j < 8; ++j) v[j] = (short)f2bf(tile[cg + j][w] * st[cg + j]);
    *(bf16x8*)(xt + (((size_t)bh * 64 + w) << 9) + ic * 32 + cg) = v;
}

// ---------------- main conv: implicit GEMM, 128x128 tile, mfma 16x16x32 bf16 ----
// LDS layout XOR-swizzled: element (row r, k-quad q) lives at halfs r*32 + (q ^ ((r>>1)&3))*8
__global__ __launch_bounds__(256, 2)
void k_conv(const unsigned short* __restrict__ wA, const unsigned short* __restrict__ xt,
            const float* __restrict__ dcoefs,
            const float* __restrict__ noise, const float* __restrict__ nstr,
            const float* __restrict__ bias, float* __restrict__ out) {
    __shared__ __align__(16) unsigned short lA[128 * 32];
    __shared__ __align__(16) unsigned short lB[128 * 32];
    const int tid = threadIdx.x;
    const int lane = tid & 63;
    const int wave = tid >> 6;

    // XCD-aware swizzle: xcd = lid&7; within an XCD, the 4 o-blocks sharing a
    // B-tile run consecutively (o fastest), pairs (b,p_tile) ≡ xcd (mod 8).
    const int lid = blockIdx.x;
    const int xcd = lid & 7, grp = lid >> 3;
    const int o_blk = grp & 3;
    const int pair = ((grp >> 2) << 3) | xcd;      // 0..511
    const int b = pair >> 5;
    const int o0 = o_blk * 128;
    const int p0 = (pair & 31) * 128;
    const int h0 = p0 >> 6;

    // staging k-quad (XOR swizzle): lane l stages global k-quad kqs into LDS slot l&3
    const int kqs = (lane & 3) ^ ((lane >> 3) & 3);

    const unsigned short* gA0 = wA + ((size_t)(o0 + wave * 32 + (lane >> 2))) * 512 + kqs * 8;
    const unsigned short* gA1 = gA0 + 16 * 512;
    void* ldsA0 = (void*)(lA + wave * 1024);
    void* ldsA1 = (void*)(lA + wave * 1024 + 512);
    void* ldsB0 = (void*)(lB + wave * 1024);
    void* ldsB1 = (void*)(lB + wave * 1024 + 512);

    const int fm_row = (wave >> 1) * 64 + (lane & 15);
    const int fn_row = (wave & 1) * 64 + (lane & 15);
    // fragment read: col halfs = (q ^ ((r>>1)&3))*8, q = lane>>4 (independent of frag idx f)
    const int kof = (((lane >> 4) ^ ((lane >> 1) & 3)) & 3) * 8;

    f32x4 acc[4][4];
#pragma unroll
    for (int i = 0; i < 4; ++i)
#pragma unroll
        for (int j = 0; j < 4; ++j) acc[i][j] = (f32x4){0.f, 0.f, 0.f, 0.f};

    for (int t = 0; t < 9; ++t) {
        const int dy = t / 3 - 1, dx = t % 3 - 1;
        const unsigned short* gB[2];
        int adv[2];
#pragma unroll
        for (int s = 0; s < 2; ++s) {
            int pp = wave * 32 + s * 16 + (lane >> 2);   // pixel row in tile [0,127]
            int r = pp >> 6, w = pp & 63;
            int h = h0 + r + dy, ww = w + dx;
            bool valid = ((unsigned)h < 64u) && ((unsigned)ww < 64u);
            gB[s] = valid ? xt + (((size_t)b * 64 + h) * 64 + ww) * 512 + kqs * 8
                          : g_zero + kqs * 8;
            adv[s] = valid ? 32 : 0;
        }
        for (int i0 = 0; i0 < 16; ++i0) {
            __syncthreads();
            gload16(gA0, ldsA0);
            gload16(gA1, ldsA1);
            gload16(gB[0], ldsB0);
            gload16(gB[1], ldsB1);
            gA0 += 32; gA1 += 32; gB[0] += adv[0]; gB[1] += adv[1];
            asm volatile("s_waitcnt vmcnt(0)" ::: "memory");
            __syncthreads();

            bf16x8 af[4], bfr[4];
#pragma unroll
            for (int f = 0; f < 4; ++f)
                af[f] = *(const bf16x8*)&lA[(fm_row + f * 16) * 32 + kof];
#pragma unroll
            for (int f = 0; f < 4; ++f)
                bfr[f] = *(const bf16x8*)&lB[(fn_row + f * 16) * 32 + kof];
#pragma unroll
            for (int fm = 0; fm < 4; ++fm)
#pragma unroll
                for (int fn = 0; fn < 4; ++fn)
                    acc[fm][fn] = __builtin_amdgcn_mfma_f32_16x16x32_bf16(
                        af[fm], bfr[fn], acc[fm][fn], 0, 0, 0);
        }
        gA0 += 261632; gA1 += 261632;   // next tap plane (COUT*512) minus the 512 advanced
    }

    const float ns = nstr[0];
    const float* dcb = dcoefs + b * 512;
#pragma unroll
    for (int fm = 0; fm < 4; ++fm) {
        int ob = o0 + (wave >> 1) * 64 + fm * 16 + (lane >> 4) * 4;
#pragma unroll
        for (int fn = 0; fn < 4; ++fn) {
            int p = p0 + (wave & 1) * 64 + fn * 16 + (lane & 15);
            float nval = noise[p] * ns;
#pragma unroll
            for (int rg = 0; rg < 4; ++rg) {
                int o = ob + rg;
                float v = acc[fm][fn][rg] * dcb[o] + nval + bias[o];
                v = (v > 0.f ? v : 0.2f * v) * 1.41421356f;
                out[((size_t)(b * COUT + o) << 12) + p] = v;
            }
        }
    }
}

// -------- fallback: fully self-contained fp32 conv (touches NO workspace) --------
__global__ void k_conv_naive(const float* __restrict__ x, const float* __restrict__ w,
                             const float* __restrict__ weight,
                             const float* __restrict__ aw, const float* __restrict__ ab,
                             const float* __restrict__ noise, const float* __restrict__ nstr,
                             const float* __restrict__ bias, float* __restrict__ out) {
    const int o = blockIdx.x, b = blockIdx.y;
    __shared__ float ss[512];
    __shared__ float red[256];
    const float* wv = w + b * 512;
    for (int i = threadIdx.x; i < 512; i += 256) {
        const float* arow = aw + (size_t)i * 512;
        float acc = 0.f;
        for (int k = 0; k < 512; ++k) acc += wv[k] * arow[k];
        ss[i] = acc * 0.04419417382415922f + ab[i];
    }
    __syncthreads();
    float part = 0.f;
    for (int i = threadIdx.x; i < 512; i += 256) {
        float s = ss[i], sq = 0.f;
#pragma unroll
        for (int k = 0; k < 9; ++k) { float v = weight[((size_t)o * 512 + i) * 9 + k]; sq += v * v; }
        part += s * s * sq;
    }
    red[threadIdx.x] = part;
    __syncthreads();
    for (int st = 128; st; st >>= 1) {
        if (threadIdx.x < st) red[threadIdx.x] += red[threadIdx.x + st];
        __syncthreads();
    }
    const float dcoef = rsqrtf(red[0] + 1e-8f);

    float acc[16];
#pragma unroll
    for (int j = 0; j < 16; ++j) acc[j] = 0.f;
    for (int i = 0; i < 512; ++i) {
        const float s = ss[i];
        float wk[9];
#pragma unroll
        for (int k = 0; k < 9; ++k) wk[k] = weight[((size_t)o * 512 + i) * 9 + k] * s;
        const float* xp = x + ((size_t)b * 512 + i) * 4096;
#pragma unroll
        for (int j = 0; j < 16; ++j) {
            const int p = (j << 8) + threadIdx.x;
            const int h = p >> 6, ww = p & 63;
            float a = acc[j];
#pragma unroll
            for (int ky = 0; ky < 3; ++ky) {
                int hh = h + ky - 1;
                if ((unsigned)hh < 64u) {
#pragma unroll
                    for (int kx = 0; kx < 3; ++kx) {
                        int wv2 = ww + kx - 1;
                        if ((unsigned)wv2 < 64u) a += wk[ky * 3 + kx] * xp[hh * 64 + wv2];
                    }
                }
            }
            acc[j] = a;
        }
    }
    const float ns = nstr[0], bs = bias[o];
#pragma unroll
    for (int j = 0; j < 16; ++j) {
        int p = (j << 8) + threadIdx.x;
        float v = acc[j] * dcoef + noise[p] * ns + bs;
        v = (v > 0.f ? v : 0.2f * v) * 1.41421356f;
        out[((size_t)(b * COUT + o) << 12) + p] = v;
    }
}

extern "C" void kernel_launch(void* const* d_in, const int* in_sizes, int n_in,
                              void* d_out, int out_size, void* d_ws, size_t ws_size,
                              hipStream_t stream) {
    const float* x   = (const float*)d_in[0];
    const float* w   = (const float*)d_in[1];
    const float* wt  = (const float*)d_in[2];
    const float* aw  = (const float*)d_in[3];
    const float* ab  = (const float*)d_in[4];
    const float* bs  = (const float*)d_in[5];
    const float* nc  = (const float*)d_in[6];
    const float* nst = (const float*)d_in[7];
    float* out = (float*)d_out;

    char* ws = (char*)d_ws;
    float* styles = (float*)ws;                                  // 32 KB
    float* dcoefs = (float*)(ws + 32 * 1024);                    // 32 KB
    float* wsq    = (float*)(ws + 64 * 1024);                    // 1 MB
    unsigned short* wA = (unsigned short*)(ws + (2 << 20));      // 4.7 MB
    unsigned short* xt = (unsigned short*)(ws + (2 << 20) + 4718592ull); // 67.1 MB
    const size_t need = (size_t)(2 << 20) + 4718592ull + 67108864ull;    // ~70.5 MB

    if (d_ws != nullptr && ws_size >= need) {
        k_prep1<<<2560, 256, 0, stream>>>(w, aw, ab, wt, styles, wA, wsq);
        k_dcoefs<<<2048, 256, 0, stream>>>(wsq, styles, dcoefs);
        k_xpose<<<dim3(1024, 16), 256, 0, stream>>>(x, styles, xt);
        k_conv<<<2048, 256, 0, stream>>>(wA, xt, dcoefs, nc, nst, bs, out);
    } else {
        k_conv_naive<<<dim3(512, 16), 256, 0, stream>>>(x, w, wt, aw, ab, nc, nst, bs, out);
    }
}